// Round 1
// 460.038 us; speedup vs baseline: 1.0833x; 1.0833x over previous
//
#include <hip/hip_runtime.h>
#include <stdint.h>

typedef _Float16 half8 __attribute__((ext_vector_type(8)));   // fp16 MFMA frag (4 VGPRs)
typedef __attribute__((ext_vector_type(4))) float f32x4;      // MFMA accumulator
typedef __attribute__((ext_vector_type(8))) unsigned short us8;

__device__ inline unsigned short f2h(float x) {
  _Float16 h = (_Float16)x;                 // v_cvt_f16_f32, RNE
  return __builtin_bit_cast(unsigned short, h);
}

// ---- async global->LDS, 16B per lane ----
__device__ inline void ld16(const unsigned short* g, unsigned short* l) {
  __builtin_amdgcn_global_load_lds(
      (const __attribute__((address_space(1))) unsigned int*)g,
      (__attribute__((address_space(3))) unsigned int*)l, 16, 0, 0);
}

// ---- fp32 -> fp16 cast, 8 elems/thread ----
__global__ void k_cast16(const float* __restrict__ in, unsigned short* __restrict__ o, long n8) {
  long i = (long)blockIdx.x * blockDim.x + threadIdx.x;
  if (i >= n8) return;
  float4 a = ((const float4*)in)[i * 2];
  float4 b = ((const float4*)in)[i * 2 + 1];
  us8 h;
  h[0] = f2h(a.x); h[1] = f2h(a.y); h[2] = f2h(a.z); h[3] = f2h(a.w);
  h[4] = f2h(b.x); h[5] = f2h(b.y); h[6] = f2h(b.z); h[7] = f2h(b.w);
  *(us8*)(o + i * 8) = h;
}

// ---- V [K x D] fp32  ->  VT [D x K] fp16 (per batch) ----
__global__ void k_transpose16(const float* __restrict__ V, unsigned short* __restrict__ VT,
                              int Kn, int Dn) {
  __shared__ unsigned short t[64][65];
  const int b = blockIdx.z;
  const int k0 = blockIdx.x * 64, d0 = blockIdx.y * 64;
  const int c = threadIdx.x & 63, rr = threadIdx.x >> 6;
  const float* pV = V + (long)b * Kn * Dn;
  unsigned short* pT = VT + (long)b * Dn * Kn;
#pragma unroll
  for (int i = 0; i < 16; ++i) {
    int r = rr + i * 4;
    t[r][c] = f2h(pV[(long)(k0 + r) * Dn + d0 + c]);
  }
  __syncthreads();
#pragma unroll
  for (int i = 0; i < 16; ++i) {
    int r = rr + i * 4;
    pT[(long)(d0 + r) * Kn + k0 + c] = t[c][r];
  }
}

// ============================================================================
// 256x256-tile GEMM, 8 waves (2M x 4N), BK=32, 4 LDS buffers (128 KiB),
// 4-phase/2-K-tile schedule with counted vmcnt (T3+T4), LDS XOR swizzle (T2),
// setprio around MFMA clusters (T5), bijective XCD swizzle (T1).
// C[M,N] = A[M,Kin] * B[N,Kin]^T, fp16 MFMA 16x16x32, fp32 out.
// STATS==1: per-(b, q-tile, row-half) column max/sumexp partials (16 slots).
// ============================================================================

#define SBAR() __builtin_amdgcn_s_barrier()
#define SCHED0() __builtin_amdgcn_sched_barrier(0)
#define LGKM0() do { asm volatile("s_waitcnt lgkmcnt(0)" ::: "memory"); SCHED0(); } while (0)
#define VMC(n) do { asm volatile("s_waitcnt vmcnt(" #n ")" ::: "memory"); } while (0)

template <int STATS>
__launch_bounds__(512, 2)
__global__ void k_gemm_bt(const unsigned short* __restrict__ A,
                          const unsigned short* __restrict__ B,
                          float* __restrict__ C, float2* __restrict__ ps,
                          int N, int Kin, long sA, long sB, long sC) {
  // 4 buffers x (A 256x32 + B 256x32) fp16 = 4 x 32 KiB = 128 KiB
  __shared__ unsigned short sAb[4][256 * 32];
  __shared__ unsigned short sBb[4][256 * 32];

  const int tid = threadIdx.x;
  const int lane = tid & 63, wave = tid >> 6;
  const int wr = wave >> 2, wc = wave & 3;   // 2 x 4 wave grid; wave owns 128x64
  const int l15 = lane & 15;

  // ---- T1: bijective XCD swizzle (all grids here have nwg % 8 == 0) ----
  const int nx = gridDim.x, ny = gridDim.y;
  int wg = ((int)blockIdx.z * ny + blockIdx.y) * nx + blockIdx.x;
  const int nwg = nx * ny * (int)gridDim.z;
  wg = (wg & 7) * (nwg >> 3) + (wg >> 3);
  const int tn = wg % nx, tm = (wg / nx) % ny, b = wg / (nx * ny);

  const unsigned short* pA = A + b * sA + (long)tm * 256 * Kin;
  const unsigned short* pB = B + b * sB + (long)tn * 256 * Kin;
  float* pC = C + b * sC;

  // ---- staging addressing: linear LDS dest, inverse-swizzled global source
  // swizzle: col ^= ((row>>1)&3)<<3  (involution, keeps 8-half chunks intact)
  const int rlo = tid >> 2;                                  // dest row 0..127
  const int csw = ((tid & 3) * 8) ^ (((rlo >> 1) & 3) << 3); // src col chunk
  const long ga = (long)rlo * Kin + csw;
  const long gh = (long)128 * Kin;                           // row-half stride

  // ---- fragment ds_read offsets (swizzled on the read side, same XOR) ----
  const int ksw = ((lane >> 4) * 8) ^ (((l15 >> 1) & 3) << 3);
  const int aoff = (wr * 128 + l15) * 32 + ksw;   // + m*512 per 16-row step
  const int boff = (wc * 64 + l15) * 32 + ksw;    // + n*512 per 16-row step

#define STG_A(t, q) do { \
    ld16(pA + ga + (long)(t) * 32, &sAb[q][tid * 8]); \
    ld16(pA + ga + gh + (long)(t) * 32, &sAb[q][4096 + tid * 8]); } while (0)
#define STG_B(t, q) do { \
    ld16(pB + ga + (long)(t) * 32, &sBb[q][tid * 8]); \
    ld16(pB + ga + gh + (long)(t) * 32, &sBb[q][4096 + tid * 8]); } while (0)

#define LDA8(q, m) (*(const half8*)&sAb[q][aoff + (m) * 512])
#define LDB8(q, n) (*(const half8*)&sBb[q][boff + (n) * 512])

  f32x4 acc[8][4];
#pragma unroll
  for (int i = 0; i < 8; ++i)
#pragma unroll
    for (int j = 0; j < 4; ++j)
#pragma unroll
      for (int r = 0; r < 4; ++r) acc[i][j][r] = 0.f;

  half8 fa0, fa1, fa2, fa3, fb0, fb1, fb2, fb3;

#define MFMA4(m, a) \
  acc[m][0] = __builtin_amdgcn_mfma_f32_16x16x32_f16(a, fb0, acc[m][0], 0, 0, 0); \
  acc[m][1] = __builtin_amdgcn_mfma_f32_16x16x32_f16(a, fb1, acc[m][1], 0, 0, 0); \
  acc[m][2] = __builtin_amdgcn_mfma_f32_16x16x32_f16(a, fb2, acc[m][2], 0, 0, 0); \
  acc[m][3] = __builtin_amdgcn_mfma_f32_16x16x32_f16(a, fb3, acc[m][3], 0, 0, 0);

#define PH_READ_AB(q) \
  fa0 = LDA8(q, 0); fa1 = LDA8(q, 1); fa2 = LDA8(q, 2); fa3 = LDA8(q, 3); \
  fb0 = LDB8(q, 0); fb1 = LDB8(q, 1); fb2 = LDB8(q, 2); fb3 = LDB8(q, 3);

#define PH_READ_A(q) \
  fa0 = LDA8(q, 4); fa1 = LDA8(q, 5); fa2 = LDA8(q, 6); fa3 = LDA8(q, 7);

#define PH_MFMA_LO \
  __builtin_amdgcn_s_setprio(1); \
  MFMA4(0, fa0) MFMA4(1, fa1) MFMA4(2, fa2) MFMA4(3, fa3) \
  __builtin_amdgcn_s_setprio(0);

#define PH_MFMA_HI \
  __builtin_amdgcn_s_setprio(1); \
  MFMA4(4, fa0) MFMA4(5, fa1) MFMA4(6, fa2) MFMA4(7, fa3) \
  __builtin_amdgcn_s_setprio(0);

  const int nt = Kin >> 5;   // K-tiles of 32
  const int ni = nt >> 1;    // iterations (2 K-tiles each)

  // prologue: stage K-tiles 0,1; retire K-tile 0 (leave 4 in flight)
  STG_A(0, 0); STG_B(0, 0);
  STG_A(1, 1); STG_B(1, 1);
  VMC(4); SCHED0(); SBAR();

  for (int it = 0; it + 1 < ni; ++it) {
    const int t0 = it * 2;
    const int q0 = t0 & 3, q1 = q0 + 1;
    const int r0 = q0 ^ 2, r1 = q1 ^ 2;
    // phase 1: read Ktile t0 (m0-3 + all B), stage A(t0+2)
    PH_READ_AB(q0)
    STG_A(t0 + 2, r0);
    SCHED0(); SBAR(); LGKM0();
    PH_MFMA_LO
    SCHED0(); SBAR();
    // phase 2: read Ktile t0 (m4-7), stage B(t0+2); retire Ktile t0+1
    PH_READ_A(q0)
    STG_B(t0 + 2, r0);
    SCHED0(); SBAR(); LGKM0();
    PH_MFMA_HI
    VMC(4); SCHED0(); SBAR();
    // phase 3: read Ktile t0+1 (m0-3 + all B), stage A(t0+3)
    PH_READ_AB(q1)
    STG_A(t0 + 3, r1);
    SCHED0(); SBAR(); LGKM0();
    PH_MFMA_LO
    SCHED0(); SBAR();
    // phase 4: read Ktile t0+1 (m4-7), stage B(t0+3); retire Ktile t0+2
    PH_READ_A(q1)
    STG_B(t0 + 3, r1);
    SCHED0(); SBAR(); LGKM0();
    PH_MFMA_HI
    VMC(4); SCHED0(); SBAR();
  }
  // peeled final iteration (no staging)
  {
    const int q0 = (nt - 2) & 3, q1 = q0 + 1;
    PH_READ_AB(q0)
    SCHED0(); SBAR(); LGKM0();
    PH_MFMA_LO
    SCHED0(); SBAR();
    PH_READ_A(q0)
    SCHED0(); SBAR(); LGKM0();
    PH_MFMA_HI
    VMC(0); SCHED0(); SBAR();   // last K-tile's staging fully landed
    PH_READ_AB(q1)
    LGKM0();
    PH_MFMA_LO
    PH_READ_A(q1)
    LGKM0();
    PH_MFMA_HI
  }

  // ---- epilogue: C write (C/D layout: col=lane&15, row=(lane>>4)*4+r) ----
  const int crow0 = tm * 256 + wr * 128 + (lane >> 4) * 4;
  const int ccol0 = tn * 256 + wc * 64 + l15;
#pragma unroll
  for (int m = 0; m < 8; ++m)
#pragma unroll
    for (int n = 0; n < 4; ++n)
#pragma unroll
      for (int r = 0; r < 4; ++r)
        pC[(long)(crow0 + m * 16 + r) * N + ccol0 + n * 16] = acc[m][n][r];

  if constexpr (STATS) {
    // per-wave column stats over this wave's 128 rows; 16 slots per (b, col)
#pragma unroll
    for (int n = 0; n < 4; ++n) {
      float mx = -3.0e38f;
#pragma unroll
      for (int m = 0; m < 8; ++m)
#pragma unroll
        for (int r = 0; r < 4; ++r) mx = fmaxf(mx, acc[m][n][r]);
      mx = fmaxf(mx, __shfl_xor(mx, 16, 64));
      mx = fmaxf(mx, __shfl_xor(mx, 32, 64));
      float l = 0.f;
#pragma unroll
      for (int m = 0; m < 8; ++m)
#pragma unroll
        for (int r = 0; r < 4; ++r) l += __expf(acc[m][n][r] - mx);
      l += __shfl_xor(l, 16, 64);
      l += __shfl_xor(l, 32, 64);
      if (lane < 16) {
        int col = tn * 256 + wc * 64 + n * 16 + lane;
        ps[((long)(b * 16 + tm * 2 + wr)) * N + col] = make_float2(mx, l);
      }
    }
  }
}

// ---- combine 16 per-tile partials -> (M_k, 1/L_k) ----
__global__ void k_stats_combine(const float2* __restrict__ ps, float2* __restrict__ st, int Kn) {
  const long i = (long)blockIdx.x * blockDim.x + threadIdx.x;  // over nb*Kn
  const int b = (int)(i / Kn), k = (int)(i % Kn);
  float M = -3.0e38f;
#pragma unroll
  for (int j = 0; j < 16; ++j) M = fmaxf(M, ps[((long)(b * 16 + j)) * Kn + k].x);
  float L = 0.f;
#pragma unroll
  for (int j = 0; j < 16; ++j) {
    float2 v = ps[((long)(b * 16 + j)) * Kn + k];
    L += v.y * __expf(v.x - M);
  }
  st[i] = make_float2(M, 1.0f / L);
}

// ---- P = exp(S - M_k) * invL_k -> fp16, 8 elems/thread ----
__global__ void k_pcomp(const float* __restrict__ S, const float2* __restrict__ st,
                        unsigned short* __restrict__ P) {
  const long i = (long)blockIdx.x * blockDim.x + threadIdx.x;
  const long r = i >> 8;               // row = b*2048 + q  (2048/8 = 256 thr/row)
  const int kb = (int)(i & 255) * 8;
  const int b = (int)(r >> 11);
  const float* sp = S + r * 2048 + kb;
  float4 s0 = *(const float4*)sp;
  float4 s1 = *(const float4*)(sp + 4);
  const float2* tp = st + (long)b * 2048 + kb;
  us8 o;
  float sv[8] = {s0.x, s0.y, s0.z, s0.w, s1.x, s1.y, s1.z, s1.w};
#pragma unroll
  for (int j = 0; j < 8; ++j) {
    float2 t = tp[j];
    o[j] = f2h(__expf(sv[j] - t.x) * t.y);
  }
  *(us8*)(P + r * 2048 + kb) = o;
}

extern "C" void kernel_launch(void* const* d_in, const int* in_sizes, int n_in,
                              void* d_out, int out_size, void* d_ws, size_t ws_size,
                              hipStream_t stream) {
  const float* Q = (const float*)d_in[0];
  const float* Kp = (const float*)d_in[1];
  const float* V = (const float*)d_in[2];
  float* out = (float*)d_out;

  constexpr int Bb = 8, Qn = 2048, Kn = 2048, Dn = 1024;
  constexpr long QD = (long)Qn * Dn, KD = (long)Kn * Dn, QK = (long)Qn * Kn, DK = (long)Dn * Kn;

  // per-batch workspace need (bytes)
  const size_t per = 3 * (size_t)(QD * 2)   // q16, k16, vt
                   + (size_t)(QK * 4)       // S
                   + (size_t)(QK * 2)       // P
                   + (size_t)(16 * Kn * 8)  // partial stats (16 slots)
                   + (size_t)(Kn * 8);      // final stats
  int cb = 8;
  while (cb > 1 && (size_t)cb * per > ws_size) cb >>= 1;

  char* w = (char*)d_ws;
  unsigned short* q16 = (unsigned short*)w; w += (size_t)cb * QD * 2;
  unsigned short* k16 = (unsigned short*)w; w += (size_t)cb * KD * 2;
  unsigned short* vt  = (unsigned short*)w; w += (size_t)cb * DK * 2;
  float* S            = (float*)w;          w += (size_t)cb * QK * 4;
  unsigned short* P   = (unsigned short*)w; w += (size_t)cb * QK * 2;
  float2* ps          = (float2*)w;         w += (size_t)cb * 16 * Kn * 8;
  float2* st          = (float2*)w;

  for (int b0 = 0; b0 < Bb; b0 += cb) {
    int nb = (cb < Bb - b0) ? cb : (Bb - b0);
    long n8 = (long)nb * QD / 8;
    k_cast16<<<(int)(n8 / 256), 256, 0, stream>>>(Q + b0 * QD, q16, n8);
    k_cast16<<<(int)(n8 / 256), 256, 0, stream>>>(Kp + b0 * KD, k16, n8);
    k_transpose16<<<dim3(Kn / 64, Dn / 64, nb), 256, 0, stream>>>(V + b0 * KD, vt, Kn, Dn);
    k_gemm_bt<1><<<dim3(Kn / 256, Qn / 256, nb), 512, 0, stream>>>(
        q16, k16, S, ps, Kn, Dn, QD, KD, QK);
    k_stats_combine<<<nb * Kn / 256, 256, 0, stream>>>(ps, st, Kn);
    k_pcomp<<<(int)((long)nb * QK / 8 / 256), 256, 0, stream>>>(S, st, P);
    k_gemm_bt<0><<<dim3(Dn / 256, Qn / 256, nb), 512, 0, stream>>>(
        P, vt, out + b0 * QD, nullptr, Dn, Kn, QK, DK, QD);
  }
}

// Round 2
// 411.531 us; speedup vs baseline: 1.2110x; 1.1179x over previous
//
#include <hip/hip_runtime.h>
#include <stdint.h>

typedef _Float16 half8 __attribute__((ext_vector_type(8)));   // fp16 MFMA frag (4 VGPRs)
typedef __attribute__((ext_vector_type(4))) float f32x4;      // MFMA accumulator
typedef __attribute__((ext_vector_type(8))) unsigned short us8;

__device__ inline unsigned short f2h(float x) {
  _Float16 h = (_Float16)x;                 // v_cvt_f16_f32, RNE
  return __builtin_bit_cast(unsigned short, h);
}

// ---- async global->LDS, 16B per lane ----
__device__ inline void ld16(const unsigned short* g, unsigned short* l) {
  __builtin_amdgcn_global_load_lds(
      (const __attribute__((address_space(1))) unsigned int*)g,
      (__attribute__((address_space(3))) unsigned int*)l, 16, 0, 0);
}

// ---- fp32 -> fp16 cast, 8 elems/thread ----
__global__ void k_cast16(const float* __restrict__ in, unsigned short* __restrict__ o, long n8) {
  long i = (long)blockIdx.x * blockDim.x + threadIdx.x;
  if (i >= n8) return;
  float4 a = ((const float4*)in)[i * 2];
  float4 b = ((const float4*)in)[i * 2 + 1];
  us8 h;
  h[0] = f2h(a.x); h[1] = f2h(a.y); h[2] = f2h(a.z); h[3] = f2h(a.w);
  h[4] = f2h(b.x); h[5] = f2h(b.y); h[6] = f2h(b.z); h[7] = f2h(b.w);
  *(us8*)(o + i * 8) = h;
}

// ---- V [K x D] fp32  ->  VT [D x K] fp16 (per batch) ----
__global__ void k_transpose16(const float* __restrict__ V, unsigned short* __restrict__ VT,
                              int Kn, int Dn) {
  __shared__ unsigned short t[64][65];
  const int b = blockIdx.z;
  const int k0 = blockIdx.x * 64, d0 = blockIdx.y * 64;
  const int c = threadIdx.x & 63, rr = threadIdx.x >> 6;
  const float* pV = V + (long)b * Kn * Dn;
  unsigned short* pT = VT + (long)b * Dn * Kn;
#pragma unroll
  for (int i = 0; i < 16; ++i) {
    int r = rr + i * 4;
    t[r][c] = f2h(pV[(long)(k0 + r) * Dn + d0 + c]);
  }
  __syncthreads();
#pragma unroll
  for (int i = 0; i < 16; ++i) {
    int r = rr + i * 4;
    pT[(long)(d0 + r) * Kn + k0 + c] = t[c][r];
  }
}

// ============================================================================
// 256x256-tile GEMM, 8 waves (2M x 4N), BK=32, 4 LDS buffers (128 KiB).
// Software-pipelined fragment double-buffer: ds_reads for phase p+1 issue
// BEFORE phase p's MFMA cluster; ONE barrier + ONE counted vmcnt per K-tile;
// no explicit lgkmcnt (compiler emits counted lgkm per MFMA).
// T1 XCD swizzle, T2 LDS XOR swizzle, T5 setprio retained.
// C[M,N] = A[M,Kin] * B[N,Kin]^T, fp16 MFMA 16x16x32, fp32 out.
// STATS==1: per-(b, q-tile, row-half) column max/sumexp partials (16 slots).
// ============================================================================

#define SBAR() __builtin_amdgcn_s_barrier()
#define SCHED0() __builtin_amdgcn_sched_barrier(0)
#define VMC(n) do { asm volatile("s_waitcnt vmcnt(" #n ")" ::: "memory"); } while (0)

template <int STATS>
__launch_bounds__(512, 2)
__global__ void k_gemm_bt(const unsigned short* __restrict__ A,
                          const unsigned short* __restrict__ B,
                          float* __restrict__ C, float2* __restrict__ ps,
                          int N, int Kin, long sA, long sB, long sC) {
  // 4 buffers x (A 256x32 + B 256x32) fp16 = 4 x 32 KiB = 128 KiB
  __shared__ unsigned short sAb[4][256 * 32];
  __shared__ unsigned short sBb[4][256 * 32];

  const int tid = threadIdx.x;
  const int lane = tid & 63, wave = tid >> 6;
  const int wr = wave >> 2, wc = wave & 3;   // 2 x 4 wave grid; wave owns 128x64
  const int l15 = lane & 15;

  // ---- T1: bijective XCD swizzle (all grids here have nwg % 8 == 0) ----
  const int nx = gridDim.x, ny = gridDim.y;
  int wg = ((int)blockIdx.z * ny + blockIdx.y) * nx + blockIdx.x;
  const int nwg = nx * ny * (int)gridDim.z;
  wg = (wg & 7) * (nwg >> 3) + (wg >> 3);
  const int tn = wg % nx, tm = (wg / nx) % ny, b = wg / (nx * ny);

  const unsigned short* pA = A + b * sA + (long)tm * 256 * Kin;
  const unsigned short* pB = B + b * sB + (long)tn * 256 * Kin;
  float* pC = C + b * sC;

  // ---- staging addressing: linear LDS dest, inverse-swizzled global source
  // swizzle: col ^= ((row>>1)&3)<<3  (involution, keeps 8-half chunks intact)
  const int rlo = tid >> 2;                                  // dest row 0..127
  const int csw = ((tid & 3) * 8) ^ (((rlo >> 1) & 3) << 3); // src col chunk
  const long ga = (long)rlo * Kin + csw;
  const long gh = (long)128 * Kin;                           // row-half stride

  // ---- fragment ds_read offsets (swizzled on the read side, same XOR) ----
  const int ksw = ((lane >> 4) * 8) ^ (((l15 >> 1) & 3) << 3);
  const int aoff = (wr * 128 + l15) * 32 + ksw;   // + m*512 per 16-row step
  const int boff = (wc * 64 + l15) * 32 + ksw;    // + n*512 per 16-row step

#define STG(t, q) do { \
    ld16(pA + ga + (long)(t) * 32, &sAb[q][tid * 8]); \
    ld16(pA + ga + gh + (long)(t) * 32, &sAb[q][4096 + tid * 8]); \
    ld16(pB + ga + (long)(t) * 32, &sBb[q][tid * 8]); \
    ld16(pB + ga + gh + (long)(t) * 32, &sBb[q][4096 + tid * 8]); } while (0)

#define LDA8(q, m) (*(const half8*)&sAb[q][aoff + (m) * 512])
#define LDB8(q, n) (*(const half8*)&sBb[q][boff + (n) * 512])

  f32x4 acc[8][4];
#pragma unroll
  for (int i = 0; i < 8; ++i)
#pragma unroll
    for (int j = 0; j < 4; ++j)
#pragma unroll
      for (int r = 0; r < 4; ++r) acc[i][j][r] = 0.f;

  // fragment register sets: aL/bC double-buffered across tiles, aH single
  half8 aL[2][4], bC[2][4], aH[4];

#define READ_LO(s, q) \
  aL[s][0] = LDA8(q, 0); aL[s][1] = LDA8(q, 1); aL[s][2] = LDA8(q, 2); aL[s][3] = LDA8(q, 3); \
  bC[s][0] = LDB8(q, 0); bC[s][1] = LDB8(q, 1); bC[s][2] = LDB8(q, 2); bC[s][3] = LDB8(q, 3);

#define READ_HI(q) \
  aH[0] = LDA8(q, 4); aH[1] = LDA8(q, 5); aH[2] = LDA8(q, 6); aH[3] = LDA8(q, 7);

#define MFMA_ROW(m, a, s) \
  acc[m][0] = __builtin_amdgcn_mfma_f32_16x16x32_f16(a, bC[s][0], acc[m][0], 0, 0, 0); \
  acc[m][1] = __builtin_amdgcn_mfma_f32_16x16x32_f16(a, bC[s][1], acc[m][1], 0, 0, 0); \
  acc[m][2] = __builtin_amdgcn_mfma_f32_16x16x32_f16(a, bC[s][2], acc[m][2], 0, 0, 0); \
  acc[m][3] = __builtin_amdgcn_mfma_f32_16x16x32_f16(a, bC[s][3], acc[m][3], 0, 0, 0);

#define MFMA_LO(s) \
  __builtin_amdgcn_s_setprio(1); \
  MFMA_ROW(0, aL[s][0], s) MFMA_ROW(1, aL[s][1], s) \
  MFMA_ROW(2, aL[s][2], s) MFMA_ROW(3, aL[s][3], s) \
  __builtin_amdgcn_s_setprio(0);

#define MFMA_HI(s) \
  __builtin_amdgcn_s_setprio(1); \
  MFMA_ROW(4, aH[0], s) MFMA_ROW(5, aH[1], s) \
  MFMA_ROW(6, aH[2], s) MFMA_ROW(7, aH[3], s) \
  __builtin_amdgcn_s_setprio(0);

  // Per tile t (set s = t&1):
  //   LO: issue aH reads (buf t&3), issue STG(t+2), MFMA_LO on aL[s]/bC[s]
  //   HI: vmcnt(4) [tile t+1 staged, this wave] ; barrier [all waves] ;
  //       issue next tile's aL/bC reads (buf (t+1)&3) ; MFMA_HI on aH/bC[s]
  // Hazards: buffer (t+2)&3 (holds tile t-2) last READ+consumed before the
  // barrier in tile t-1's HI -> one barrier/tile suffices. vmcnt ledger:
  // 4 loads/tile, 2 tiles in flight, steady-state wait = vmcnt(4).
#define TILE_MAIN(t, s, sn) \
  READ_HI((t) & 3); \
  STG((t) + 2, ((t) + 2) & 3); \
  MFMA_LO(s) \
  VMC(4); SBAR(); SCHED0(); \
  READ_LO(sn, ((t) + 1) & 3); \
  MFMA_HI(s)

  const int nt = Kin >> 5;   // K-tiles of 32 (even, >= 4)

  // prologue: stage tiles 0,1; wait tile 0 (all waves); preload tile 0 frags
  STG(0, 0);
  STG(1, 1);
  VMC(4); SBAR(); SCHED0();
  READ_LO(0, 0);

  for (int t = 0; t + 3 < nt; t += 2) {
    TILE_MAIN(t, 0, 1);
    TILE_MAIN(t + 1, 1, 0);
  }
  // peeled last pair (tiles nt-2, nt-1): no staging; drain vmcnt fully
  {
    READ_HI((nt - 2) & 3);
    MFMA_LO(0)
    VMC(0); SBAR(); SCHED0();
    READ_LO(1, (nt - 1) & 3);
    MFMA_HI(0)
    READ_HI((nt - 1) & 3);
    MFMA_LO(1)
    MFMA_HI(1)
  }

  // ---- epilogue: C write (C/D layout: col=lane&15, row=(lane>>4)*4+r) ----
  const int crow0 = tm * 256 + wr * 128 + (lane >> 4) * 4;
  const int ccol0 = tn * 256 + wc * 64 + l15;
#pragma unroll
  for (int m = 0; m < 8; ++m)
#pragma unroll
    for (int n = 0; n < 4; ++n)
#pragma unroll
      for (int r = 0; r < 4; ++r)
        pC[(long)(crow0 + m * 16 + r) * N + ccol0 + n * 16] = acc[m][n][r];

  if constexpr (STATS) {
    // per-wave column stats over this wave's 128 rows; 16 slots per (b, col)
#pragma unroll
    for (int n = 0; n < 4; ++n) {
      float mx = -3.0e38f;
#pragma unroll
      for (int m = 0; m < 8; ++m)
#pragma unroll
        for (int r = 0; r < 4; ++r) mx = fmaxf(mx, acc[m][n][r]);
      mx = fmaxf(mx, __shfl_xor(mx, 16, 64));
      mx = fmaxf(mx, __shfl_xor(mx, 32, 64));
      float l = 0.f;
#pragma unroll
      for (int m = 0; m < 8; ++m)
#pragma unroll
        for (int r = 0; r < 4; ++r) l += __expf(acc[m][n][r] - mx);
      l += __shfl_xor(l, 16, 64);
      l += __shfl_xor(l, 32, 64);
      if (lane < 16) {
        int col = tn * 256 + wc * 64 + n * 16 + lane;
        ps[((long)(b * 16 + tm * 2 + wr)) * N + col] = make_float2(mx, l);
      }
    }
  }
}

// ---- combine 16 per-tile partials -> (M_k, 1/L_k) ----
__global__ void k_stats_combine(const float2* __restrict__ ps, float2* __restrict__ st, int Kn) {
  const long i = (long)blockIdx.x * blockDim.x + threadIdx.x;  // over nb*Kn
  const int b = (int)(i / Kn), k = (int)(i % Kn);
  float M = -3.0e38f;
#pragma unroll
  for (int j = 0; j < 16; ++j) M = fmaxf(M, ps[((long)(b * 16 + j)) * Kn + k].x);
  float L = 0.f;
#pragma unroll
  for (int j = 0; j < 16; ++j) {
    float2 v = ps[((long)(b * 16 + j)) * Kn + k];
    L += v.y * __expf(v.x - M);
  }
  st[i] = make_float2(M, 1.0f / L);
}

// ---- P = exp(S - M_k) * invL_k -> fp16, 8 elems/thread ----
__global__ void k_pcomp(const float* __restrict__ S, const float2* __restrict__ st,
                        unsigned short* __restrict__ P) {
  const long i = (long)blockIdx.x * blockDim.x + threadIdx.x;
  const long r = i >> 8;               // row = b*2048 + q  (2048/8 = 256 thr/row)
  const int kb = (int)(i & 255) * 8;
  const int b = (int)(r >> 11);
  const float* sp = S + r * 2048 + kb;
  float4 s0 = *(const float4*)sp;
  float4 s1 = *(const float4*)(sp + 4);
  const float2* tp = st + (long)b * 2048 + kb;
  us8 o;
  float sv[8] = {s0.x, s0.y, s0.z, s0.w, s1.x, s1.y, s1.z, s1.w};
#pragma unroll
  for (int j = 0; j < 8; ++j) {
    float2 t = tp[j];
    o[j] = f2h(__expf(sv[j] - t.x) * t.y);
  }
  *(us8*)(P + r * 2048 + kb) = o;
}

extern "C" void kernel_launch(void* const* d_in, const int* in_sizes, int n_in,
                              void* d_out, int out_size, void* d_ws, size_t ws_size,
                              hipStream_t stream) {
  const float* Q = (const float*)d_in[0];
  const float* Kp = (const float*)d_in[1];
  const float* V = (const float*)d_in[2];
  float* out = (float*)d_out;

  constexpr int Bb = 8, Qn = 2048, Kn = 2048, Dn = 1024;
  constexpr long QD = (long)Qn * Dn, KD = (long)Kn * Dn, QK = (long)Qn * Kn, DK = (long)Dn * Kn;

  // per-batch workspace need (bytes)
  const size_t per = 3 * (size_t)(QD * 2)   // q16, k16, vt
                   + (size_t)(QK * 4)       // S
                   + (size_t)(QK * 2)       // P
                   + (size_t)(16 * Kn * 8)  // partial stats (16 slots)
                   + (size_t)(Kn * 8);      // final stats
  int cb = 8;
  while (cb > 1 && (size_t)cb * per > ws_size) cb >>= 1;

  char* w = (char*)d_ws;
  unsigned short* q16 = (unsigned short*)w; w += (size_t)cb * QD * 2;
  unsigned short* k16 = (unsigned short*)w; w += (size_t)cb * KD * 2;
  unsigned short* vt  = (unsigned short*)w; w += (size_t)cb * DK * 2;
  float* S            = (float*)w;          w += (size_t)cb * QK * 4;
  unsigned short* P   = (unsigned short*)w; w += (size_t)cb * QK * 2;
  float2* ps          = (float2*)w;         w += (size_t)cb * 16 * Kn * 8;
  float2* st          = (float2*)w;

  for (int b0 = 0; b0 < Bb; b0 += cb) {
    int nb = (cb < Bb - b0) ? cb : (Bb - b0);
    long n8 = (long)nb * QD / 8;
    k_cast16<<<(int)(n8 / 256), 256, 0, stream>>>(Q + b0 * QD, q16, n8);
    k_cast16<<<(int)(n8 / 256), 256, 0, stream>>>(Kp + b0 * KD, k16, n8);
    k_transpose16<<<dim3(Kn / 64, Dn / 64, nb), 256, 0, stream>>>(V + b0 * KD, vt, Kn, Dn);
    k_gemm_bt<1><<<dim3(Kn / 256, Qn / 256, nb), 512, 0, stream>>>(
        q16, k16, S, ps, Kn, Dn, QD, KD, QK);
    k_stats_combine<<<nb * Kn / 256, 256, 0, stream>>>(ps, st, Kn);
    k_pcomp<<<(int)((long)nb * QK / 8 / 256), 256, 0, stream>>>(S, st, P);
    k_gemm_bt<0><<<dim3(Dn / 256, Qn / 256, nb), 512, 0, stream>>>(
        P, vt, out + b0 * QD, nullptr, Dn, Kn, QK, DK, QD);
  }
}